// Round 14
// baseline (666.748 us; speedup 1.0000x reference)
//
#include <hip/hip_runtime.h>
#include <math.h>

namespace {
constexpr int LSEQ = 32;
constexpr int CDIM = 64;
constexpr int HDIM = 128;
constexpr int FDIM = 32;
constexpr float TWO_PI = 6.28318530717958647692f;

typedef float fv2 __attribute__((ext_vector_type(2)));
typedef float fv4 __attribute__((ext_vector_type(4)));

__device__ __forceinline__ float sigf(float x) { return 1.0f / (1.0f + __expf(-x)); }
__device__ __forceinline__ float tanh_fast(float x) { return 1.0f - 2.0f / (__expf(2.0f * x) + 1.0f); }
}

// Two-group stagger: 512 threads = 2 groups x 256, each group owns 2 seqs with
// fully disjoint LDS. Group B's 16-phase schedule is rotated by 8 slots, so
// every shared barrier interval packs two DIFFERENT phases (mogrify||gates,
// state||mogrify, ...) -> latency chains overlap. Phases per group per step:
// 0..9 mogrify(x,h,x,h,x as partial+reduce), 10 gates, 11 gate-reduce,
// 12 state, 13 out-partial, 14 out-reduce, 15 x-commit.
__global__ __launch_bounds__(512, 1)
void sfm_lstm_r14(const float* __restrict__ x,
                  const float* __restrict__ Q, const float* __restrict__ R,
                  const float* __restrict__ Wi, const float* __restrict__ bi,
                  const float* __restrict__ Wg, const float* __restrict__ bg,
                  const float* __restrict__ Wste, const float* __restrict__ bste,
                  const float* __restrict__ Wfre, const float* __restrict__ bfre,
                  const float* __restrict__ Wom, const float* __restrict__ bom,
                  const float* __restrict__ Wo, const float* __restrict__ bo,
                  const float* __restrict__ Wa, const float* __restrict__ ba,
                  const float* __restrict__ Wout, const float* __restrict__ bout,
                  float* __restrict__ out)
{
    const int t = threadIdx.x;
    const int blk = blockIdx.x;
    const bool isA = (t < 256);
    const int g = t >> 8;
    const int u = t & 255;

    __shared__ float sQ[HDIM * CDIM];                  // Q[k][c] 32 KB (shared)
    __shared__ float sR[CDIM * HDIM];                  // R[k][j] 32 KB (shared)
    __shared__ __align__(16) float soh_s[2][320][2];   // per group: x|h|ct
    __shared__ __align__(16) float sit_s[2][HDIM][2];
    __shared__ __align__(16) float schat_s[2][HDIM][2];
    __shared__ __align__(16) float sfste_s[2][HDIM][2];
    __shared__ __align__(16) float sffre_s[2][2][FDIM];   // seq-major
    __shared__ __align__(16) float scos_s[2][2][FDIM];
    __shared__ __align__(16) float ssin_s[2][2][FDIM];
    __shared__ __align__(16) float spart_s[2][2048];
    __shared__ float swa[FDIM];

    #pragma unroll
    for (int i = 0; i < 16; ++i) sQ[t + 512 * i] = Q[t + 512 * i];
    #pragma unroll
    for (int i = 0; i < 16; ++i) sR[t + 512 * i] = R[t + 512 * i];
    if (t < FDIM) swa[t] = Wa[t];

    // group-local views
    float (*soh)[2]   = soh_s[g];
    float (*sit)[2]   = sit_s[g];
    float (*schat)[2] = schat_s[g];
    float (*sfste)[2] = sfste_s[g];
    float (*sffre)[FDIM] = sffre_s[g];
    float (*scosv)[FDIM] = scos_s[g];
    float (*ssinv)[FDIM] = ssin_s[g];
    float* spart = spart_s[g];
    const float* xg = x + ((size_t)blk * 4 + 2 * g) * LSEQ * CDIM;

    soh[64 + (u >> 1)][u & 1] = 0.0f;                  // h = 0
    if (u < 128) soh[u >> 1][u & 1] = xg[(size_t)(u & 1) * LSEQ * CDIM + (u >> 1)];

    // ---- roles (within group, 256 threads, 2 seqs) ----
    const int mc = u & 63,  mks = u >> 6;              // mog-x: col, k-slice(4x32)
    const int mj = u & 127, mhs = u >> 7;              // mog-h: col, k-slice(2x32)
    const int srow = mj, sseq = mhs;                   // state: (row, seq)

    const int gq = u >> 1, kh = u & 1;                 // gates: quad cols, k-half
    const int gcol0 = 4 * gq;
    const float* wGp = Wi; int gstr = HDIM;
    int greg = -1, grcl = 0; const float* bG = bi;
    if (u < 224) {
        if      (gcol0 < 128) { wGp = Wi   + gcol0;       gstr = HDIM; }
        else if (gcol0 < 256) { wGp = Wg   + gcol0 - 128; gstr = HDIM; }
        else if (gcol0 < 384) { wGp = Wste + gcol0 - 256; gstr = HDIM; }
        else if (gcol0 < 416) { wGp = Wfre + gcol0 - 384; gstr = FDIM; }
        else                  { wGp = Wom  + gcol0 - 416; gstr = FDIM; }
        wGp += (size_t)(96 * kh) * gstr;
        const int rc0 = gcol0 + 2 * kh;
        if      (rc0 < 128) { bG = bi;   grcl = rc0;       greg = 0; }
        else if (rc0 < 256) { bG = bg;   grcl = rc0 - 128; greg = 1; }
        else if (rc0 < 384) { bG = bste; grcl = rc0 - 256; greg = 2; }
        else if (rc0 < 416) { bG = bfre; grcl = rc0 - 384; greg = 3; }
        else                { bG = bom;  grcl = rc0 - 416; greg = 4; }
    }
    const float gb0 = (u < 224) ? bG[grcl] : 0.0f;
    const float gb1 = (u < 224) ? bG[grcl + 1] : 0.0f;

    const int og = u & 31, oks = u >> 5;               // out: quad cols, 8 k-slices
    const float* woP = Wo + 4 * og + (size_t)(40 * oks) * HDIM;
    const float bo_r = bo[u >> 1];
    const int pl = u - 224;                            // prefetch lane (u>=224)
    const float ba0 = ba[0];

    fv2 re2[FDIM / 2], im2[FDIM / 2];
    #pragma unroll
    for (int j = 0; j < FDIM / 2; ++j) { re2[j] = 0.0f; im2[j] = 0.0f; }
    float xn00 = 0.f, xn01 = 0.f, xn10 = 0.f, xn11 = 0.f;

    // ---- phase bodies ----
    auto MXP = [&]() {                                 // mog-x partial
        const int k0 = mks * 32;
        fv2 acc = 0.0f;
        #pragma unroll
        for (int kk = 0; kk < 32; ++kk) {
            const float qv = sQ[(k0 + kk) * CDIM + mc];
            const fv2 h2 = *(const fv2*)&soh[64 + k0 + kk][0];
            acc += h2 * qv;
        }
        *(fv2*)&spart[mks * 128 + mc * 2] = acc;
    };
    auto MXR = [&]() {                                 // mog-x reduce (128 thr)
        if (u < 128) {
            const float v = spart[u] + spart[128 + u] + spart[256 + u] + spart[384 + u];
            soh[u >> 1][u & 1] *= 2.0f * sigf(v);
        }
    };
    auto MHP = [&]() {                                 // mog-h partial
        const int k0 = mhs * 32;
        fv2 acc = 0.0f;
        #pragma unroll
        for (int kk = 0; kk < 32; ++kk) {
            const float rv = sR[(k0 + kk) * HDIM + mj];
            const fv2 x2 = *(const fv2*)&soh[k0 + kk][0];
            acc += x2 * rv;
        }
        *(fv2*)&spart[mhs * 256 + mj * 2] = acc;
    };
    auto MHR = [&]() {                                 // mog-h reduce (256 thr)
        const float v = spart[u] + spart[256 + u];
        soh[64 + (u >> 1)][u & 1] *= 2.0f * sigf(v);
    };
    auto GP = [&](int tsg) {                           // gates partial + x prefetch
        if (u < 224) {
            fv2 a0 = 0.0f, a1 = 0.0f, a2 = 0.0f, a3 = 0.0f;
            const float* wp = wGp;
            const int kb = kh * 96;
            #pragma unroll 8
            for (int kk = 0; kk < 96; ++kk) {
                const fv4 w4 = *(const fv4*)wp; wp += gstr;
                const fv2 i2 = *(const fv2*)&soh[kb + kk][0];
                a0 += i2 * w4.x; a1 += i2 * w4.y; a2 += i2 * w4.z; a3 += i2 * w4.w;
            }
            float* sp = &spart[(kh * 112 + gq) * 8];
            *(fv2*)(sp)     = a0; *(fv2*)(sp + 2) = a1;
            *(fv2*)(sp + 4) = a2; *(fv2*)(sp + 6) = a3;
        } else if (tsg + 1 < LSEQ) {
            const float* xp = xg + (size_t)(tsg + 1) * CDIM;
            xn00 = xp[2 * pl];  xn01 = xp[2 * pl + 1];
            xn10 = xp[(size_t)LSEQ * CDIM + 2 * pl];
            xn11 = xp[(size_t)LSEQ * CDIM + 2 * pl + 1];
        }
    };
    auto GR = [&]() {                                  // gate reduce (224 thr)
        if (u < 224) {
            const fv4 p0 = *(const fv4*)&spart[gq * 8 + kh * 4];
            const fv4 p1 = *(const fv4*)&spart[896 + gq * 8 + kh * 4];
            fv4 v = p0 + p1;
            v.x += gb0; v.y += gb0; v.z += gb1; v.w += gb1;
            if (greg == 4) {
                const float o0 = TWO_PI * sigf(v.x), o1 = TWO_PI * sigf(v.y);
                const float o2 = TWO_PI * sigf(v.z), o3 = TWO_PI * sigf(v.w);
                scosv[0][grcl] = __cosf(o0);     ssinv[0][grcl] = __sinf(o0);
                scosv[1][grcl] = __cosf(o1);     ssinv[1][grcl] = __sinf(o1);
                scosv[0][grcl + 1] = __cosf(o2); ssinv[0][grcl + 1] = __sinf(o2);
                scosv[1][grcl + 1] = __cosf(o3); ssinv[1][grcl + 1] = __sinf(o3);
            } else if (greg == 3) {
                sffre[0][grcl] = sigf(v.x);     sffre[1][grcl] = sigf(v.y);
                sffre[0][grcl + 1] = sigf(v.z); sffre[1][grcl + 1] = sigf(v.w);
            } else {
                float* d = (greg == 0) ? &sit[0][0] : (greg == 1) ? &schat[0][0] : &sfste[0][0];
                *(fv4*)&d[grcl * 2] = (fv4){sigf(v.x), sigf(v.y), sigf(v.z), sigf(v.w)};
            }
        }
    };
    auto ST = [&]() {                                  // complex state + c_t
        const float ic = sit[srow][sseq] * schat[srow][sseq];
        const float fs = sfste[srow][sseq];
        float acc = 0.f;
        #pragma unroll
        for (int j2 = 0; j2 < FDIM / 2; ++j2) {
            const fv2 fr2 = *(const fv2*)&sffre[sseq][2 * j2];
            const fv2 cv2 = *(const fv2*)&scosv[sseq][2 * j2];
            const fv2 sv2 = *(const fv2*)&ssinv[sseq][2 * j2];
            const fv2 ft2 = fr2 * fs;
            re2[j2] = ft2 * re2[j2] + cv2 * ic;
            im2[j2] = ft2 * im2[j2] + sv2 * ic;
            const fv2 m2 = re2[j2] * re2[j2] + im2[j2] * im2[j2];
            acc = fmaf(sqrtf(m2.x), swa[2 * j2], acc);
            acc = fmaf(sqrtf(m2.y), swa[2 * j2 + 1], acc);
        }
        soh[192 + srow][sseq] = tanh_fast(acc + ba0);
    };
    auto OP = [&]() {                                  // out partial (256 thr)
        fv2 a0 = 0.0f, a1 = 0.0f, a2 = 0.0f, a3 = 0.0f;
        const float* wp = woP;
        const int kb = 40 * oks;
        #pragma unroll 8
        for (int kk = 0; kk < 40; ++kk) {
            const fv4 w4 = *(const fv4*)wp; wp += HDIM;
            const fv2 i2 = *(const fv2*)&soh[kb + kk][0];
            a0 += i2 * w4.x; a1 += i2 * w4.y; a2 += i2 * w4.z; a3 += i2 * w4.w;
        }
        float* sp = &spart[oks * 256 + og * 8];
        *(fv2*)(sp)     = a0; *(fv2*)(sp + 2) = a1;
        *(fv2*)(sp + 4) = a2; *(fv2*)(sp + 6) = a3;
    };
    auto ORD = [&]() {                                 // out reduce -> h
        float v = 0.f;
        #pragma unroll
        for (int ks = 0; ks < 8; ++ks) v += spart[ks * 256 + u];
        const float o = sigf(v + bo_r);
        soh[64 + (u >> 1)][u & 1] = o * tanh_fast(soh[192 + (u >> 1)][u & 1]);
    };
    auto XC = [&](int tsg) {                           // commit prefetched x
        if (u >= 224 && tsg + 1 < LSEQ) {
            soh[2 * pl][0] = xn00; soh[2 * pl + 1][0] = xn01;
            soh[2 * pl][1] = xn10; soh[2 * pl + 1][1] = xn11;
        }
    };

    __syncthreads();

    // ---- staggered schedule: A at phase s, B at phase (s+8) mod 16 ----
    for (int ms = 0; ms <= LSEQ; ++ms) {
        const bool aA = ms < LSEQ;                     // A works on step ms
        const bool aB0 = ms >= 1;                      // B slots 0-7: step ms-1
        const bool aB8 = ms < LSEQ;                    // B slots 8-15: step ms

        if (isA ? aA : aB0) MXP();  __syncthreads();   // s0:  A mx1p | B mx3p
        if (isA ? aA : aB0) MXR();  __syncthreads();   // s1:  A mx1r | B mx3r
        if (isA) { if (aA) MHP(); } else { if (aB0) GP(ms - 1); }  __syncthreads(); // s2
        if (isA) { if (aA) MHR(); } else { if (aB0) GR(); }        __syncthreads(); // s3
        if (isA) { if (aA) MXP(); } else { if (aB0) ST(); }        __syncthreads(); // s4
        if (isA) { if (aA) MXR(); } else { if (aB0) OP(); }        __syncthreads(); // s5
        if (isA) { if (aA) MHP(); } else { if (aB0) ORD(); }       __syncthreads(); // s6
        if (isA) { if (aA) MHR(); } else { if (aB0) XC(ms - 1); }  __syncthreads(); // s7
        if (isA ? aA : aB8) MXP();  __syncthreads();   // s8:  A mx3p | B mx1p
        if (isA ? aA : aB8) MXR();  __syncthreads();   // s9:  A mx3r | B mx1r
        if (isA) { if (aA) GP(ms); } else { if (aB8) MHP(); }      __syncthreads(); // s10
        if (isA) { if (aA) GR(); } else { if (aB8) MHR(); }        __syncthreads(); // s11
        if (isA) { if (aA) ST(); } else { if (aB8) MXP(); }        __syncthreads(); // s12
        if (isA) { if (aA) OP(); } else { if (aB8) MXR(); }        __syncthreads(); // s13
        if (isA) { if (aA) ORD(); } else { if (aB8) MHP(); }       __syncthreads(); // s14
        if (isA) { if (aA) XC(ms); } else { if (aB8) MHR(); }      __syncthreads(); // s15
    }

    // ---- out = h_last @ Wout + bout, one wave per sequence (per group) ----
    if (u < 128) {
        const int w = u >> 6, l = u & 63;
        float p = soh[64 + l][w] * Wout[l] + soh[128 + l][w] * Wout[64 + l];
        #pragma unroll
        for (int off = 32; off > 0; off >>= 1) p += __shfl_xor(p, off);
        if (l == 0) out[blk * 4 + 2 * g + w] = p + bout[0];
    }
}

extern "C" void kernel_launch(void* const* d_in, const int* in_sizes, int n_in,
                              void* d_out, int out_size, void* d_ws, size_t ws_size,
                              hipStream_t stream) {
    const float* x    = (const float*)d_in[0];
    const float* Q    = (const float*)d_in[1];
    const float* R    = (const float*)d_in[2];
    const float* Wi   = (const float*)d_in[3];
    const float* bi   = (const float*)d_in[4];
    const float* Wg   = (const float*)d_in[5];
    const float* bg   = (const float*)d_in[6];
    const float* Wste = (const float*)d_in[7];
    const float* bste = (const float*)d_in[8];
    const float* Wfre = (const float*)d_in[9];
    const float* bfre = (const float*)d_in[10];
    const float* Wom  = (const float*)d_in[11];
    const float* bom  = (const float*)d_in[12];
    const float* Wo   = (const float*)d_in[13];
    const float* bo   = (const float*)d_in[14];
    const float* Wa   = (const float*)d_in[15];
    const float* ba   = (const float*)d_in[16];
    const float* Wout = (const float*)d_in[17];
    const float* bout = (const float*)d_in[18];
    float* out = (float*)d_out;

    sfm_lstm_r14<<<dim3(256), dim3(512), 0, stream>>>(
        x, Q, R, Wi, bi, Wg, bg, Wste, bste, Wfre, bfre, Wom, bom,
        Wo, bo, Wa, ba, Wout, bout, out);
}

// Round 15
// 355.029 us; speedup vs baseline: 1.8780x; 1.8780x over previous
//
#include <hip/hip_runtime.h>
#include <math.h>

namespace {
constexpr int LSEQ = 32;
constexpr int CDIM = 64;
constexpr int HDIM = 128;
constexpr int FDIM = 32;
constexpr float TWO_PI = 6.28318530717958647692f;

typedef float fv2 __attribute__((ext_vector_type(2)));
typedef float fv4 __attribute__((ext_vector_type(4)));

__device__ __forceinline__ float sigf(float x) { return 1.0f / (1.0f + __expf(-x)); }
__device__ __forceinline__ float tanh_fast(float x) { return 1.0f - 2.0f / (__expf(2.0f * x) + 1.0f); }
}

// R13 frame (376us: S=4, 512 thr, pk_fma packing) + mogrify weights in
// registers: qreg[16]/rreg[16] are per-lane-constant slices of Q/R, killing
// the 16 b32 LDS weight reads per wave per mogrify phase (~3.7Kcy/step of
// LDS-pipe time) and shortening the serial mogrify chains. sQ/sR staging
// deleted. Gate loop unroll 8->4 to shrink transient VGPR peak (in-flight
// w4 buffers) so the cache fits under the 128-VGPR cap (65536/512 law).
__global__ __launch_bounds__(512, 1)
void sfm_lstm_r15(const float* __restrict__ x,
                  const float* __restrict__ Q, const float* __restrict__ R,
                  const float* __restrict__ Wi, const float* __restrict__ bi,
                  const float* __restrict__ Wg, const float* __restrict__ bg,
                  const float* __restrict__ Wste, const float* __restrict__ bste,
                  const float* __restrict__ Wfre, const float* __restrict__ bfre,
                  const float* __restrict__ Wom, const float* __restrict__ bom,
                  const float* __restrict__ Wo, const float* __restrict__ bo,
                  const float* __restrict__ Wa, const float* __restrict__ ba,
                  const float* __restrict__ Wout, const float* __restrict__ bout,
                  float* __restrict__ out)
{
    const int t = threadIdx.x;
    const int blk = blockIdx.x;

    // soh[320][4]: rows 0..63 = xt, 64..191 = h, 192..319 = c_t  ([dim][seq])
    __shared__ __align__(16) float soh[320][4];
    __shared__ __align__(16) float sit[HDIM][4];
    __shared__ __align__(16) float schat[HDIM][4];
    __shared__ __align__(16) float sfste[HDIM][4];
    __shared__ __align__(16) float sffre[4][FDIM];     // seq-major for fv2 reads
    __shared__ __align__(16) float scosv[4][FDIM];
    __shared__ __align__(16) float ssinv[4][FDIM];
    __shared__ __align__(16) float spart[8192];        // 32 KB partials
    __shared__ float swa[FDIM];

    if (t < FDIM) swa[t] = Wa[t];
    soh[64 + (t >> 2)][t & 3] = 0.0f;                  // h = 0

    // state role: (row r7, seq sA), f-pairs packed
    const int r7 = t & 127, sA = t >> 7;
    fv2 re2[FDIM / 2], im2[FDIM / 2];
    #pragma unroll
    for (int j = 0; j < FDIM / 2; ++j) { re2[j] = 0.0f; im2[j] = 0.0f; }

    // mogrify roles + register-cached per-lane weight slices
    const int mc = t & 63,  mksx = t >> 6;             // x: col mc, 8 k-slices of 16
    const int mj = t & 127, mksh = t >> 7;             // h: col mj, 4 k-slices of 16
    float qreg[16], rreg[16];
    #pragma unroll
    for (int kk = 0; kk < 16; ++kk) qreg[kk] = Q[(mksx * 16 + kk) * CDIM + mc];
    #pragma unroll
    for (int kk = 0; kk < 16; ++kk) rreg[kk] = R[(mksh * 16 + kk) * HDIM + mj];

    // gate PARTIAL role (t<448): group gg owns cols 4gg..4gg+3, k-slice gks
    const int gks = t / 112, gg = t - gks * 112;
    const int gcol0 = 4 * gg;
    const float* wPt = Wi; int strP = HDIM;
    if      (gcol0 < 128) { wPt = Wi   + gcol0;         strP = HDIM; }
    else if (gcol0 < 256) { wPt = Wg   + (gcol0 - 128); strP = HDIM; }
    else if (gcol0 < 384) { wPt = Wste + (gcol0 - 256); strP = HDIM; }
    else if (gcol0 < 416) { wPt = Wfre + (gcol0 - 384); strP = FDIM; }
    else                  { wPt = Wom  + (gcol0 - 416); strP = FDIM; }
    wPt += (size_t)(48 * gks) * strP;

    // gate REDUCE role (t<448): col = t
    const float* bG = bi; int reg = -1, gcol = 0;
    if      (t < 128) { bG = bi;   gcol = t;       reg = 0; }
    else if (t < 256) { bG = bg;   gcol = t - 128; reg = 1; }
    else if (t < 384) { bG = bste; gcol = t - 256; reg = 2; }
    else if (t < 416) { bG = bfre; gcol = t - 384; reg = 3; }
    else if (t < 448) { bG = bom;  gcol = t - 416; reg = 4; }
    const float gb = (reg >= 0) ? bG[gcol] : 0.0f;

    // out roles: 16 k-slices x 32 col-groups
    const int oks = t >> 5, og = t & 31;
    const float* woPt = Wo + 4 * og + (size_t)(20 * oks) * HDIM;
    const float bo_r = (t < 128) ? bo[t] : 0.0f;

    const float ba0 = ba[0];
    const float* xbase = x + (size_t)blk * 4 * LSEQ * CDIM;
    const int pl = t - 448;                            // prefetch lane (wave 7)

    // prologue: x(ts=0)
    if (t < 256) soh[t & 63][t >> 6] = xbase[((t >> 6) * LSEQ) * CDIM + (t & 63)];
    __syncthreads();

    for (int ts = 0; ts < LSEQ; ++ts) {
        // ---- mogrify x,h,x,h,x (weights in registers, pk_fma packed) ----
        #pragma unroll
        for (int m = 0; m < 5; ++m) {
            if ((m & 1) == 0) {
                const int k0 = mksx * 16;
                fv2 a01 = 0.0f, a23 = 0.0f;
                #pragma unroll
                for (int kk = 0; kk < 16; ++kk) {
                    const fv4 h4 = *(const fv4*)&soh[64 + k0 + kk][0];
                    a01 += h4.lo * qreg[kk]; a23 += h4.hi * qreg[kk];
                }
                float* sp = &spart[mksx * 256 + mc * 4];
                *(fv2*)(sp) = a01; *(fv2*)(sp + 2) = a23;
                __syncthreads();
                if (t < 256) {
                    float v = 0.f;
                    #pragma unroll
                    for (int i = 0; i < 8; ++i) v += spart[i * 256 + t];
                    soh[t >> 2][t & 3] = 2.0f * sigf(v) * soh[t >> 2][t & 3];
                }
                __syncthreads();
            } else {
                const int k0 = mksh * 16;
                fv2 a01 = 0.0f, a23 = 0.0f;
                #pragma unroll
                for (int kk = 0; kk < 16; ++kk) {
                    const fv4 x4 = *(const fv4*)&soh[k0 + kk][0];
                    a01 += x4.lo * rreg[kk]; a23 += x4.hi * rreg[kk];
                }
                float* sp = &spart[mksh * 512 + mj * 4];
                *(fv2*)(sp) = a01; *(fv2*)(sp + 2) = a23;
                __syncthreads();
                {
                    const float v = spart[t] + spart[512 + t] + spart[1024 + t] + spart[1536 + t];
                    soh[64 + (t >> 2)][t & 3] = 2.0f * sigf(v) * soh[64 + (t >> 2)][t & 3];
                }
                __syncthreads();
            }
        }

        // ---- gate partials (t<448): 48 float4 loads, 8 pk_fma each ----
        float xn0 = 0.f, xn1 = 0.f, xn2 = 0.f, xn3 = 0.f;
        if (t < 448) {
            fv2 a0_01 = 0.0f, a0_23 = 0.0f, a1_01 = 0.0f, a1_23 = 0.0f;
            fv2 a2_01 = 0.0f, a2_23 = 0.0f, a3_01 = 0.0f, a3_23 = 0.0f;
            const float* wp = wPt;
            const int kb = 48 * gks;
            #pragma unroll 4
            for (int kk = 0; kk < 48; ++kk) {
                const fv4 w4 = *(const fv4*)wp; wp += strP;
                const fv4 i4 = *(const fv4*)&soh[kb + kk][0];
                const fv2 i01 = i4.lo, i23 = i4.hi;
                a0_01 += i01 * w4.x; a0_23 += i23 * w4.x;
                a1_01 += i01 * w4.y; a1_23 += i23 * w4.y;
                a2_01 += i01 * w4.z; a2_23 += i23 * w4.z;
                a3_01 += i01 * w4.w; a3_23 += i23 * w4.w;
            }
            float* sp = &spart[(gks * 448 + gcol0) * 4];
            *(fv2*)(sp)      = a0_01; *(fv2*)(sp + 2)  = a0_23;
            *(fv2*)(sp + 4)  = a1_01; *(fv2*)(sp + 6)  = a1_23;
            *(fv2*)(sp + 8)  = a2_01; *(fv2*)(sp + 10) = a2_23;
            *(fv2*)(sp + 12) = a3_01; *(fv2*)(sp + 14) = a3_23;
        } else if (ts + 1 < LSEQ) {
            xn0 = xbase[(0 * LSEQ + ts + 1) * CDIM + pl];
            xn1 = xbase[(1 * LSEQ + ts + 1) * CDIM + pl];
            xn2 = xbase[(2 * LSEQ + ts + 1) * CDIM + pl];
            xn3 = xbase[(3 * LSEQ + ts + 1) * CDIM + pl];
        }
        __syncthreads();

        // ---- gate reduce (t<448): col t, 4 seqs ----
        if (reg >= 0) {
            fv2 v01 = 0.0f, v23 = 0.0f;
            #pragma unroll
            for (int ks = 0; ks < 4; ++ks) {
                const float* pp = &spart[(ks * 448 + t) * 4];
                v01 += *(const fv2*)pp; v23 += *(const fv2*)(pp + 2);
            }
            const float v0 = v01.x + gb, v1 = v01.y + gb;
            const float v2 = v23.x + gb, v3 = v23.y + gb;
            if (reg == 4) {
                const float o0 = TWO_PI * sigf(v0), o1 = TWO_PI * sigf(v1);
                const float o2 = TWO_PI * sigf(v2), o3 = TWO_PI * sigf(v3);
                scosv[0][gcol] = __cosf(o0); ssinv[0][gcol] = __sinf(o0);
                scosv[1][gcol] = __cosf(o1); ssinv[1][gcol] = __sinf(o1);
                scosv[2][gcol] = __cosf(o2); ssinv[2][gcol] = __sinf(o2);
                scosv[3][gcol] = __cosf(o3); ssinv[3][gcol] = __sinf(o3);
            } else if (reg == 3) {
                sffre[0][gcol] = sigf(v0); sffre[1][gcol] = sigf(v1);
                sffre[2][gcol] = sigf(v2); sffre[3][gcol] = sigf(v3);
            } else {
                float* d = (reg == 0) ? &sit[0][0] : (reg == 1) ? &schat[0][0] : &sfste[0][0];
                *(fv4*)&d[gcol * 4] = (fv4){sigf(v0), sigf(v1), sigf(v2), sigf(v3)};
            }
        }
        __syncthreads();

        // ---- complex state + amplitude @ Wa -> c_t (f-pairs packed) ----
        {
            const float ic = sit[r7][sA] * schat[r7][sA];
            const float fs = sfste[r7][sA];
            float acc = 0.f;
            #pragma unroll
            for (int j = 0; j < FDIM / 2; ++j) {
                const fv2 fr2 = *(const fv2*)&sffre[sA][2 * j];
                const fv2 cv2 = *(const fv2*)&scosv[sA][2 * j];
                const fv2 sv2 = *(const fv2*)&ssinv[sA][2 * j];
                const fv2 ft2 = fr2 * fs;
                re2[j] = ft2 * re2[j] + cv2 * ic;
                im2[j] = ft2 * im2[j] + sv2 * ic;
                const fv2 m2 = re2[j] * re2[j] + im2[j] * im2[j];
                acc = fmaf(sqrtf(m2.x), swa[2 * j], acc);
                acc = fmaf(sqrtf(m2.y), swa[2 * j + 1], acc);
            }
            soh[192 + r7][sA] = tanh_fast(acc + ba0);
        }
        __syncthreads();

        // ---- out partials: 20 float4 loads, 8 pk_fma each ----
        {
            fv2 a0_01 = 0.0f, a0_23 = 0.0f, a1_01 = 0.0f, a1_23 = 0.0f;
            fv2 a2_01 = 0.0f, a2_23 = 0.0f, a3_01 = 0.0f, a3_23 = 0.0f;
            const float* wp = woPt;
            const int kb = 20 * oks;
            #pragma unroll 4
            for (int kk = 0; kk < 20; ++kk) {
                const fv4 w4 = *(const fv4*)wp; wp += HDIM;
                const fv4 i4 = *(const fv4*)&soh[kb + kk][0];
                const fv2 i01 = i4.lo, i23 = i4.hi;
                a0_01 += i01 * w4.x; a0_23 += i23 * w4.x;
                a1_01 += i01 * w4.y; a1_23 += i23 * w4.y;
                a2_01 += i01 * w4.z; a2_23 += i23 * w4.z;
                a3_01 += i01 * w4.w; a3_23 += i23 * w4.w;
            }
            float* sp = &spart[(oks * 128 + 4 * og) * 4];
            *(fv2*)(sp)      = a0_01; *(fv2*)(sp + 2)  = a0_23;
            *(fv2*)(sp + 4)  = a1_01; *(fv2*)(sp + 6)  = a1_23;
            *(fv2*)(sp + 8)  = a2_01; *(fv2*)(sp + 10) = a2_23;
            *(fv2*)(sp + 12) = a3_01; *(fv2*)(sp + 14) = a3_23;
        }
        __syncthreads();

        // ---- out reduce (t<128) + x commit (wave 7) ----
        if (t < 128) {
            fv2 v01 = 0.0f, v23 = 0.0f;
            #pragma unroll
            for (int ks = 0; ks < 16; ++ks) {
                const float* pp = &spart[(ks * 128 + t) * 4];
                v01 += *(const fv2*)pp; v23 += *(const fv2*)(pp + 2);
            }
            const fv4 ct4 = *(const fv4*)&soh[192 + t][0];
            fv4 h4;
            h4.x = sigf(v01.x + bo_r) * tanh_fast(ct4.x);
            h4.y = sigf(v01.y + bo_r) * tanh_fast(ct4.y);
            h4.z = sigf(v23.x + bo_r) * tanh_fast(ct4.z);
            h4.w = sigf(v23.y + bo_r) * tanh_fast(ct4.w);
            *(fv4*)&soh[64 + t][0] = h4;
        } else if (t >= 448 && ts + 1 < LSEQ) {
            soh[pl][0] = xn0; soh[pl][1] = xn1;
            soh[pl][2] = xn2; soh[pl][3] = xn3;
        }
        __syncthreads();
    }

    // ---- out = h_last @ Wout + bout, one wave per sequence ----
    if (t < 256) {
        const int w = t >> 6, l = t & 63;
        float p = soh[64 + l][w] * Wout[l] + soh[128 + l][w] * Wout[64 + l];
        #pragma unroll
        for (int off = 32; off > 0; off >>= 1) p += __shfl_xor(p, off);
        if (l == 0) out[blk * 4 + w] = p + bout[0];
    }
}

extern "C" void kernel_launch(void* const* d_in, const int* in_sizes, int n_in,
                              void* d_out, int out_size, void* d_ws, size_t ws_size,
                              hipStream_t stream) {
    const float* x    = (const float*)d_in[0];
    const float* Q    = (const float*)d_in[1];
    const float* R    = (const float*)d_in[2];
    const float* Wi   = (const float*)d_in[3];
    const float* bi   = (const float*)d_in[4];
    const float* Wg   = (const float*)d_in[5];
    const float* bg   = (const float*)d_in[6];
    const float* Wste = (const float*)d_in[7];
    const float* bste = (const float*)d_in[8];
    const float* Wfre = (const float*)d_in[9];
    const float* bfre = (const float*)d_in[10];
    const float* Wom  = (const float*)d_in[11];
    const float* bom  = (const float*)d_in[12];
    const float* Wo   = (const float*)d_in[13];
    const float* bo   = (const float*)d_in[14];
    const float* Wa   = (const float*)d_in[15];
    const float* ba   = (const float*)d_in[16];
    const float* Wout = (const float*)d_in[17];
    const float* bout = (const float*)d_in[18];
    float* out = (float*)d_out;

    sfm_lstm_r15<<<dim3(256), dim3(512), 0, stream>>>(
        x, Q, R, Wi, bi, Wg, bg, Wste, bste, Wfre, bfre, Wom, bom,
        Wo, bo, Wa, ba, Wout, bout, out);
}